// Round 1
// baseline (5405.228 us; speedup 1.0000x reference)
//
#include <hip/hip_runtime.h>

typedef _Float16 f16;
typedef _Float16 f16x4v __attribute__((ext_vector_type(4)));
typedef _Float16 f16x8  __attribute__((ext_vector_type(8)));
typedef float    f32x4  __attribute__((ext_vector_type(4)));
typedef unsigned long long u64;

#define NB 32
#define NT 512
#define NF 512
#define NH 512

// workspace layout (bytes)
static const size_t XH_BYTES  = (size_t)NB*NT*NF*2;      // 16 MiB  fp16 copy of x
static const size_t WT_BYTES  = (size_t)2*2048*1024*2;   //  8 MiB  transposed fp16 W [dir][col][k]
static const size_t HB_BYTES  = (size_t)2*4*16*512*2;    // 128 KiB h exchange [parity][grp][m][k]
static const size_t CNT_BYTES = 512;                     // barrier counters

__device__ __forceinline__ float sigf(float x){ return 1.0f/(1.0f+__expf(-x)); }
__device__ __forceinline__ float tanh_f(float x){ return 1.0f - 2.0f/(__expf(2.0f*x)+1.0f); }

__global__ void k_zero(float4* o, size_t no, uint4* z, size_t nz) {
  size_t i = (size_t)blockIdx.x*blockDim.x + threadIdx.x;
  size_t st = (size_t)gridDim.x*blockDim.x;
  float4 fz = make_float4(0.f,0.f,0.f,0.f);
  uint4  uz = make_uint4(0u,0u,0u,0u);
  for (size_t j=i; j<no; j+=st) o[j]=fz;
  for (size_t j=i; j<nz; j+=st) z[j]=uz;
}

__global__ void k_cvt(const float* __restrict__ x, f16* __restrict__ xh) {
  size_t i = ((size_t)blockIdx.x*blockDim.x + threadIdx.x)*4;
  float4 v = *(const float4*)(x+i);
  f16x4v h; h[0]=(f16)v.x; h[1]=(f16)v.y; h[2]=(f16)v.z; h[3]=(f16)v.w;
  *(f16x4v*)(xh+i) = h;
}

// W [1024][2048] f32 -> Wt[dir][col 2048][k 1024] fp16 (tiled transpose)
__global__ void k_tw(const float* __restrict__ Wfw, const float* __restrict__ Wbw,
                     f16* __restrict__ Wt) {
  __shared__ f16 tile[32][33];
  int b = blockIdx.x;
  int dir = b >> 11; int rem = b & 2047;
  int kt = rem >> 6, ct = rem & 63;
  const float* W = dir ? Wbw : Wfw;
  int tx = threadIdx.x & 31, ty0 = threadIdx.x >> 5;
  int k0 = kt*32, c0 = ct*32;
  for (int yy=ty0; yy<32; yy+=8)
    tile[yy][tx] = (f16)W[(size_t)(k0+yy)*2048 + c0 + tx];
  __syncthreads();
  f16* Wd = Wt + (size_t)dir*2048*1024;
  for (int yy=ty0; yy<32; yy+=8)
    Wd[(size_t)(c0+yy)*1024 + k0 + tx] = tile[tx][yy];
}

// Persistent recurrence kernel.
// Groups: r = blockIdx%8 in [0,4): dir = r>>1, batch-group = r&1 (16 batches).
// rank = blockIdx>>3 in [0,32): owns h-columns [16*rank, 16*rank+16).
// 4 waves: w=0,1 -> x half of K (k 0..511); w=2,3 -> h half (k 512..1023).
__global__ __launch_bounds__(256, 1) void k_rnn(
    const f16* __restrict__ xh, const f16* __restrict__ Wt,
    u64* hbuf, unsigned* cnt, const int* __restrict__ seqlen,
    const float* __restrict__ bfw, const float* __restrict__ bbw,
    float* __restrict__ out)
{
  int bid = blockIdx.x;
  int r = bid & 7, rank = bid >> 3;
  if (r >= 4) return;
  int dir = r >> 1, bg = r & 1;
  int tid = threadIdx.x;
  int w = tid >> 6, lane = tid & 63;
  int cc = lane & 15, q = lane >> 4;

  __shared__ float P[4][4][16][16];   // [wave][gate][m][n] partial sums
  __shared__ float c_st[16][16];
  __shared__ float h_st[16][16];
  __shared__ float biasS[4][16];
  __shared__ int   Ls[16];

  if (tid < 16) Ls[tid] = seqlen[bg*16 + tid];
  if (tid >= 64 && tid < 128) {
    int t2 = tid - 64;
    const float* bb = dir ? bbw : bfw;
    biasS[t2>>4][t2&15] = bb[(t2>>4)*512 + rank*16 + (t2&15)];
  }
  { int am = tid>>4, an = tid&15; c_st[am][an]=0.f; h_st[am][an]=0.f; }
  __syncthreads();

  // Persistent W fragments: wave w covers kb = w*8 .. w*8+7 (K-tiles of 32), 4 gates.
  f16x8 Wf[8][4];
  {
    const f16* Wd = Wt + (size_t)dir*2048*1024;
#pragma unroll
    for (int kk=0; kk<8; ++kk) {
      int k0 = (w*8+kk)*32 + q*4;
#pragma unroll
      for (int g=0; g<4; ++g) {
        const f16* pp = Wd + (size_t)(g*512 + rank*16 + cc)*1024 + k0;
        f16x4v lo = *(const f16x4v*)pp;
        f16x4v hi = *(const f16x4v*)(pp+16);
        f16x8 a;
        a[0]=lo[0];a[1]=lo[1];a[2]=lo[2];a[3]=lo[3];
        a[4]=hi[0];a[5]=hi[1];a[6]=hi[2];a[7]=hi[3];
        Wf[kk][g] = a;
      }
    }
  }

  int myL = Ls[cc];              // batch row for matrix loads is lane&15
  unsigned* mycnt = cnt + r*32;

  for (int s = 0; s < NT; ++s) {
    int p = s & 1;
    f32x4 acc0={0.f,0.f,0.f,0.f}, acc1=acc0, acc2=acc0, acc3=acc0;
    f16x8 Af[8];
    if (w < 2) {
      int u = (dir==0) ? s : (myL-1-s);
      u = u < 0 ? 0 : (u > NT-1 ? NT-1 : u);
      const f16* xp = xh + ((size_t)(bg*16+cc)*NT + u)*NF;
#pragma unroll
      for (int kk=0; kk<8; ++kk) {
        int k0 = (w*8+kk)*32 + q*4;
        f16x4v lo = *(const f16x4v*)(xp + k0);
        f16x4v hi = *(const f16x4v*)(xp + k0 + 16);
        f16x8 a;
        a[0]=lo[0];a[1]=lo[1];a[2]=lo[2];a[3]=lo[3];
        a[4]=hi[0];a[5]=hi[1];a[6]=hi[2];a[7]=hi[3];
        Af[kk]=a;
      }
    } else {
      u64* hp = hbuf + ((size_t)(p*4 + r)*16 + cc)*(NH/4);
#pragma unroll
      for (int kk=0; kk<8; ++kk) {
        int kh0 = ((w-2)*8+kk)*32 + q*4;
        u64 lo = __hip_atomic_load(hp + (kh0>>2),      __ATOMIC_RELAXED, __HIP_MEMORY_SCOPE_AGENT);
        u64 hi = __hip_atomic_load(hp + ((kh0+16)>>2), __ATOMIC_RELAXED, __HIP_MEMORY_SCOPE_AGENT);
        f16x4v l4 = __builtin_bit_cast(f16x4v, lo);
        f16x4v h4 = __builtin_bit_cast(f16x4v, hi);
        f16x8 a;
        a[0]=l4[0];a[1]=l4[1];a[2]=l4[2];a[3]=l4[3];
        a[4]=h4[0];a[5]=h4[1];a[6]=h4[2];a[7]=h4[3];
        Af[kk]=a;
      }
    }
#pragma unroll
    for (int kk=0; kk<8; ++kk) {
      acc0 = __builtin_amdgcn_mfma_f32_16x16x32_f16(Af[kk], Wf[kk][0], acc0, 0,0,0);
      acc1 = __builtin_amdgcn_mfma_f32_16x16x32_f16(Af[kk], Wf[kk][1], acc1, 0,0,0);
      acc2 = __builtin_amdgcn_mfma_f32_16x16x32_f16(Af[kk], Wf[kk][2], acc2, 0,0,0);
      acc3 = __builtin_amdgcn_mfma_f32_16x16x32_f16(Af[kk], Wf[kk][3], acc3, 0,0,0);
    }
#pragma unroll
    for (int rr=0; rr<4; ++rr) {
      P[w][0][q*4+rr][cc] = acc0[rr];
      P[w][1][q*4+rr][cc] = acc1[rr];
      P[w][2][q*4+rr][cc] = acc2[rr];
      P[w][3][q*4+rr][cc] = acc3[rr];
    }
    __syncthreads();

    {
      int am = tid >> 4, an = tid & 15;
      float gi = P[0][0][am][an]+P[1][0][am][an]+P[2][0][am][an]+P[3][0][am][an] + biasS[0][an];
      float gj = P[0][1][am][an]+P[1][1][am][an]+P[2][1][am][an]+P[3][1][am][an] + biasS[1][an];
      float gf = P[0][2][am][an]+P[1][2][am][an]+P[2][2][am][an]+P[3][2][am][an] + biasS[2][an];
      float go = P[0][3][am][an]+P[1][3][am][an]+P[2][3][am][an]+P[3][3][am][an] + biasS[3][an];
      int L = Ls[am];
      float hv = h_st[am][an];
      if (s < L) {
        float cp = c_st[am][an];
        float cn = sigf(gf + 1.0f)*cp + sigf(gi)*tanh_f(gj);
        float hn = sigf(go)*tanh_f(cn);
        c_st[am][an] = cn;
        h_st[am][an] = hn;
        hv = hn;
        int u = (dir==0) ? s : (L-1-s);
        out[((size_t)(bg*16+am)*NT + u)*(2*NH) + dir*NH + rank*16 + an] = hn;
      }
      float hv2 = __shfl_down(hv, 1);
      if ((an & 1) == 0) {
        f16 h0 = (f16)hv, h1 = (f16)hv2;
        unsigned pk = (unsigned)__builtin_bit_cast(unsigned short, h0)
                    | ((unsigned)__builtin_bit_cast(unsigned short, h1) << 16);
        unsigned* dst = (unsigned*)hbuf + ((((size_t)(p^1)*4 + r)*16 + am)*NH + rank*16 + an)/2;
        __hip_atomic_store(dst, pk, __ATOMIC_RELAXED, __HIP_MEMORY_SCOPE_AGENT);
      }
    }
    __syncthreads();
    if (tid == 0) {
      unsigned tgt = (unsigned)(s+1)*32u;
      __hip_atomic_fetch_add(mycnt, 1u, __ATOMIC_ACQ_REL, __HIP_MEMORY_SCOPE_AGENT);
      while (__hip_atomic_load(mycnt, __ATOMIC_ACQUIRE, __HIP_MEMORY_SCOPE_AGENT) < tgt)
        __builtin_amdgcn_s_sleep(1);
    }
    __syncthreads();
  }
}

extern "C" void kernel_launch(void* const* d_in, const int* in_sizes, int n_in,
                              void* d_out, int out_size, void* d_ws, size_t ws_size,
                              hipStream_t stream) {
  (void)in_sizes; (void)n_in; (void)out_size; (void)ws_size;
  const float* x      = (const float*)d_in[0];
  const int*   seqlen = (const int*)  d_in[1];
  const float* Wfw    = (const float*)d_in[2];
  const float* bfw    = (const float*)d_in[3];
  const float* Wbw    = (const float*)d_in[4];
  const float* bbw    = (const float*)d_in[5];
  float* out = (float*)d_out;
  unsigned char* ws = (unsigned char*)d_ws;

  f16*      xh   = (f16*)(ws);
  f16*      Wt   = (f16*)(ws + XH_BYTES);
  u64*      hbuf = (u64*)(ws + XH_BYTES + WT_BYTES);
  unsigned* cnt  = (unsigned*)(ws + XH_BYTES + WT_BYTES + HB_BYTES);

  size_t no = (size_t)NB*NT*2*NH/4;            // float4 count of d_out
  size_t nz = (HB_BYTES + CNT_BYTES)/16;       // uint4 count of h_buf + counters
  k_zero<<<dim3(2048), dim3(256), 0, stream>>>((float4*)d_out, no,
                                               (uint4*)(ws + XH_BYTES + WT_BYTES), nz);
  k_cvt<<<dim3((NB*NT*NF/4)/256), dim3(256), 0, stream>>>(x, xh);
  k_tw <<<dim3(4096), dim3(256), 0, stream>>>(Wfw, Wbw, Wt);
  k_rnn<<<dim3(256), dim3(256), 0, stream>>>(xh, Wt, hbuf, cnt, seqlen, bfw, bbw, out);
}